// Round 5
// baseline (4018.195 us; speedup 1.0000x reference)
//
#include <hip/hip_runtime.h>

typedef short b16x8 __attribute__((ext_vector_type(8)));
typedef short b16x4 __attribute__((ext_vector_type(4)));
typedef float f32x4 __attribute__((ext_vector_type(4)));
typedef unsigned short u16;

#define HN 8
#define C  256
#define W  96
#define H  96
#define KW 9
#define K  (C * KW)        // 2304
#define HW (H * W)         // 9216
#define BPITCH 264         // carry tile pitch (elems): breaks 512B-stride conflicts
#define BROWS  56          // 48 w + 8 halo
#define APITCH 2312        // W tile pitch (elems): 2304+8 pad -> bank-uniform reads
#define NSTEP  (2 * (H - 1))   // 190 sequential steps

__device__ __forceinline__ u16 f2b(float x) {
    union { float f; unsigned int u; } c; c.f = x;
    unsigned int u = c.u;
    unsigned int r = (u + 0x7fffu + ((u >> 16) & 1u)) >> 16;  // RNE
    return (u16)r;
}

// ---------------------------------------------------------------------------
// init: Wr[co][kk*256+ci] = bf16(W[co][ci][kk]); out row0 = fea row0;
//       carry0[n][w][c] = bf16(fea row0); zero the 8 barrier counters.
// ---------------------------------------------------------------------------
__global__ void init_k(const float* __restrict__ fea, const float* __restrict__ Wsrc,
                       u16* __restrict__ Wr, u16* __restrict__ carry0,
                       float* __restrict__ outp, unsigned* __restrict__ cnt)
{
    int t = blockIdx.x * 256 + threadIdx.x;
    if (t < C * K) {
        int co  = t / K;
        int rme = t - co * K;
        int kk  = rme >> 8;      // K = 9*256 exactly
        int ci  = rme & 255;
        Wr[t] = f2b(Wsrc[(co * C + ci) * KW + kk]);
    }
    if (t < HN * C * W) {
        int n   = t / (C * W);
        int rme = t - n * (C * W);
        int c   = rme / W;
        int w   = rme - c * W;
        float v = fea[(size_t)(n * C + c) * HW + w];     // h = 0
        outp[(size_t)(n * C + c) * HW + w] = v;
        carry0[((size_t)n * W + w) * C + c] = f2b(v);
    }
    if (t < HN) cnt[t * 32] = 0u;                        // 128B-spaced counters
}

// ---------------------------------------------------------------------------
// persistent cooperative kernel: 256 blocks x 64 thr (1 wave), 1 block/CU.
// block = (n, cotile, wh). All 190 recurrence steps in one launch; per-sample
// 32-block barrier between steps; 3-buffer carry rotation (read/write/spare).
// ---------------------------------------------------------------------------
__global__ __launch_bounds__(64, 1) void persist_k(
    const u16* __restrict__ Wr, const float* __restrict__ bias,
    const float* __restrict__ fea, float* __restrict__ outp,
    u16* c0, u16* c1, u16* c2, unsigned* cnt)
{
    __shared__ __align__(16) u16 Alds[16 * APITCH];       // 73,984 B
    __shared__ __align__(16) u16 Blds[BROWS * BPITCH];    // 29,568 B

    const int bx     = blockIdx.x;
    const int n      = bx >> 5;
    const int cotile = (bx >> 1) & 15;
    const int wh     = bx & 1;
    const int wbase  = wh * 48;
    const int cobase = cotile * 16;
    const int lane   = (int)threadIdx.x;
    const int col    = lane & 15;   // M-row of A, N-col of B, col of D
    const int kg     = lane >> 4;   // k-group (0..3)

    // ---- stage W slice (16 co rows x 2304) into LDS, once ----
    {
        const u16* wsp = Wr + (size_t)cobase * K;         // contiguous slice
        for (int it = 0; it < 72; ++it) {
            int t8  = it * 512 + lane * 8;
            int row = t8 / K;
            int kc  = t8 - row * K;
            b16x8 v = *(const b16x8*)(wsp + t8);
            *(b16x8*)&Alds[row * APITCH + kc] = v;
        }
    }
    // per-lane bias for its 4 output rows
    float bv[4];
    #pragma unroll
    for (int r = 0; r < 4; ++r) bv[r] = bias[cobase + kg * 4 + r];
    __syncthreads();

    unsigned* mycnt = cnt + n * 32;
    u16 *pr = c0, *pw = c1, *px = c2;

    for (int s = 0; s < NSTEP; ++s) {
        const bool  down = (s < H - 1);
        const int   row  = down ? (s + 1) : (NSTEP - 1 - s);
        const float* resp = down ? fea : outp;

        // ---- stage carry row from pr, transposed [w_local][ci], zero halo ----
        {
            const int ci = (lane & 31) * 8;
            #pragma unroll
            for (int it = 0; it < 28; ++it) {
                int r = it * 2 + (lane >> 5);      // 0..55
                int w = wbase - 4 + r;
                b16x8 v = {0, 0, 0, 0, 0, 0, 0, 0};
                if (w >= 0 && w < W)
                    v = *(const b16x8*)(pr + ((size_t)(n * W + w) * C + ci));
                *(b16x8*)&Blds[r * BPITCH + ci] = v;
            }
        }

        // ---- prefetch residual (drains in epilogue, hides under K-loop) ----
        float resv[12];
        #pragma unroll
        for (int nt = 0; nt < 3; ++nt)
            #pragma unroll
            for (int r = 0; r < 4; ++r) {
                int w  = wbase + nt * 16 + col;
                int co = cobase + kg * 4 + r;
                resv[nt * 4 + r] = resp[(size_t)(n * C + co) * HW + row * W + w];
            }

        __syncthreads();

        // ---- K-loop: 72 iters x (1 A-read + 3 B-reads + 3 MFMA) ----
        f32x4 acc0 = {0.f, 0.f, 0.f, 0.f};
        f32x4 acc1 = {0.f, 0.f, 0.f, 0.f};
        f32x4 acc2 = {0.f, 0.f, 0.f, 0.f};
        const u16* ap = Alds + col * APITCH + kg * 8;
        for (int kk = 0; kk < KW; ++kk) {
            const u16* arow = ap + kk * 256;
            const u16* lrow = &Blds[(col + kk) * BPITCH + kg * 8];
            #pragma unroll
            for (int cb = 0; cb < 8; ++cb) {
                b16x8 a  = *(const b16x8*)(arow + cb * 32);
                const u16* lp = lrow + cb * 32;
                b16x8 b0 = *(const b16x8*)(lp);
                b16x8 b1 = *(const b16x8*)(lp + 16 * BPITCH);
                b16x8 b2 = *(const b16x8*)(lp + 32 * BPITCH);
                acc0 = __builtin_amdgcn_mfma_f32_16x16x32_bf16(a, b0, acc0, 0, 0, 0);
                acc1 = __builtin_amdgcn_mfma_f32_16x16x32_bf16(a, b1, acc1, 0, 0, 0);
                acc2 = __builtin_amdgcn_mfma_f32_16x16x32_bf16(a, b2, acc2, 0, 0, 0);
            }
        }

        // ---- epilogue: bias+relu+residual; fp32 out + bf16 carry (packed) ----
        #pragma unroll
        for (int nt = 0; nt < 3; ++nt) {
            f32x4 acc = (nt == 0) ? acc0 : ((nt == 1) ? acc1 : acc2);
            int w = wbase + nt * 16 + col;
            b16x4 cv;
            #pragma unroll
            for (int r = 0; r < 4; ++r) {
                int co = cobase + kg * 4 + r;
                float y = fmaxf(acc[r] + bv[r], 0.f);
                float o = y + resv[nt * 4 + r];
                outp[(size_t)(n * C + co) * HW + row * W + w] = o;
                cv[r] = (short)f2b(o);
            }
            *(b16x4*)(pw + ((size_t)(n * W + w) * C + cobase + kg * 4)) = cv;
        }

        // ---- per-sample barrier (release stores, acquire reads), then rotate
        if (s != NSTEP - 1) {
            if (threadIdx.x == 0) {
                __hip_atomic_fetch_add(mycnt, 1u, __ATOMIC_RELEASE,
                                       __HIP_MEMORY_SCOPE_AGENT);
                unsigned tgt = (unsigned)(s + 1) * 32u;
                long guard = 0;
                while (__hip_atomic_load(mycnt, __ATOMIC_ACQUIRE,
                                         __HIP_MEMORY_SCOPE_AGENT) < tgt) {
                    __builtin_amdgcn_s_sleep(2);
                    if (++guard > (1L << 31)) break;   // hang -> wrong answer, not deadlock
                }
            }
            __syncthreads();
        }
        u16* t = pr; pr = pw; pw = px; px = t;
    }
}

// ---------------------------------------------------------------------------
extern "C" void kernel_launch(void* const* d_in, const int* in_sizes, int n_in,
                              void* d_out, int out_size, void* d_ws, size_t ws_size,
                              hipStream_t stream)
{
    const float* fea  = (const float*)d_in[0];
    const float* Wsrc = (const float*)d_in[1];
    const float* bias = (const float*)d_in[2];
    float* outp = (float*)d_out;

    u16* Wr = (u16*)d_ws;                        // 589,824 bf16
    u16* c0 = Wr + (size_t)C * K;                // 3 rotating carry buffers
    u16* c1 = c0 + (size_t)HN * W * C;
    u16* c2 = c1 + (size_t)HN * W * C;
    unsigned* cnt = (unsigned*)(c2 + (size_t)HN * W * C);  // 8 x 128B counters

    init_k<<<dim3((C * K + 255) / 256), dim3(256), 0, stream>>>(
        fea, Wsrc, Wr, c0, outp, cnt);

    void* args[] = { (void*)&Wr, (void*)&bias, (void*)&fea, (void*)&outp,
                     (void*)&c0, (void*)&c1, (void*)&c2, (void*)&cnt };
    hipLaunchCooperativeKernel((const void*)persist_k, dim3(256), dim3(64),
                               args, 0, stream);
}

// Round 8
// 3041.577 us; speedup vs baseline: 1.3211x; 1.3211x over previous
//
#include <hip/hip_runtime.h>

typedef short b16x8 __attribute__((ext_vector_type(8)));
typedef short b16x4 __attribute__((ext_vector_type(4)));
typedef float f32x4 __attribute__((ext_vector_type(4)));
typedef unsigned short u16;

#define HN 8
#define C  256
#define W  96
#define H  96
#define KW 9
#define K  (C * KW)        // 2304
#define HW (H * W)         // 9216
#define BPITCH 264         // carry tile pitch (elems): breaks 512B-stride conflicts
#define BROWS  56          // 48 w + 8 halo
#define APITCH 2312        // W tile pitch (elems): 2304+8 pad -> bank-uniform reads
#define NSTEP  (2 * (H - 1))   // 190 sequential steps

__device__ __forceinline__ u16 f2b(float x) {
    union { float f; unsigned int u; } c; c.f = x;
    unsigned int u = c.u;
    unsigned int r = (u + 0x7fffu + ((u >> 16) & 1u)) >> 16;  // RNE
    return (u16)r;
}

// ---------------------------------------------------------------------------
// init: Wr[co][kk*256+ci] = bf16(W[co][ci][kk]); out row0 = fea row0;
//       carry0[n][w][c] = bf16(fea row0); zero the 8x32 flag slots.
// ---------------------------------------------------------------------------
__global__ void init_k(const float* __restrict__ fea, const float* __restrict__ Wsrc,
                       u16* __restrict__ Wr, u16* __restrict__ carry0,
                       float* __restrict__ outp, unsigned* __restrict__ flags)
{
    int t = blockIdx.x * 256 + threadIdx.x;
    if (t < C * K) {
        int co  = t / K;
        int rme = t - co * K;
        int kk  = rme >> 8;      // K = 9*256 exactly
        int ci  = rme & 255;
        Wr[t] = f2b(Wsrc[(co * C + ci) * KW + kk]);
    }
    if (t < HN * C * W) {
        int n   = t / (C * W);
        int rme = t - n * (C * W);
        int c   = rme / W;
        int w   = rme - c * W;
        float v = fea[(size_t)(n * C + c) * HW + w];     // h = 0
        outp[(size_t)(n * C + c) * HW + w] = v;
        carry0[((size_t)n * W + w) * C + c] = f2b(v);
    }
    if (t < HN * 32) flags[t] = 0u;                      // per-writer flags
}

// ---------------------------------------------------------------------------
// persistent cooperative kernel: 256 blocks x 64 thr (1 wave), 1 block/CU.
// bx -> n = bx&7 (XCD-local sample placement), tile = bx>>3 = (cotile, wh).
// Per-sample sync: per-writer flag (release-store) + relaxed spin + one
// acquire fence. 3-buffer carry rotation (read/write/spare).
// ---------------------------------------------------------------------------
__global__ __launch_bounds__(64, 1) void persist_k(
    const u16* __restrict__ Wr, const float* __restrict__ bias,
    const float* __restrict__ fea, float* __restrict__ outp,
    u16* c0, u16* c1, u16* c2, unsigned* flags)
{
    __shared__ __align__(16) u16 Alds[16 * APITCH];       // 73,984 B
    __shared__ __align__(16) u16 Blds[BROWS * BPITCH];    // 29,568 B

    const int bx     = blockIdx.x;
    const int n      = bx & 7;      // sample -> XCD (bx%8 round-robin heuristic)
    const int tile   = bx >> 3;     // 0..31
    const int cotile = tile >> 1;
    const int wh     = tile & 1;
    const int wbase  = wh * 48;
    const int cobase = cotile * 16;
    const int lane   = (int)threadIdx.x;
    const int col    = lane & 15;   // M-row of A, N-col of B, col of D
    const int kg     = lane >> 4;   // k-group (0..3)

    // ---- stage W slice (16 co rows x 2304) into LDS, once ----
    {
        const u16* wsp = Wr + (size_t)cobase * K;         // contiguous slice
        for (int it = 0; it < 72; ++it) {
            int t8  = it * 512 + lane * 8;
            int row = t8 / K;
            int kc  = t8 - row * K;
            b16x8 v = *(const b16x8*)(wsp + t8);
            *(b16x8*)&Alds[row * APITCH + kc] = v;
        }
    }
    float bv[4];
    #pragma unroll
    for (int r = 0; r < 4; ++r) bv[r] = bias[cobase + kg * 4 + r];
    __syncthreads();

    unsigned* fl = flags + n * 32;
    u16 *pr = c0, *pw = c1, *px = c2;

    // prefetch residual for step 0 (row 1, down pass -> fea)
    float resv[12];
    #pragma unroll
    for (int nt = 0; nt < 3; ++nt)
        #pragma unroll
        for (int r = 0; r < 4; ++r) {
            int w  = wbase + nt * 16 + col;
            int co = cobase + kg * 4 + r;
            resv[nt * 4 + r] = fea[(size_t)(n * C + co) * HW + 1 * W + w];
        }

    for (int s = 0; s < NSTEP; ++s) {
        const int row = (s < H - 1) ? (s + 1) : (NSTEP - 1 - s);

        // ---- stage carry row from pr, transposed [w_local][ci], zero halo ----
        {
            const int ci = (lane & 31) * 8;
            #pragma unroll
            for (int it = 0; it < 28; ++it) {
                int r = it * 2 + (lane >> 5);      // 0..55
                int w = wbase - 4 + r;
                b16x8 v = {0, 0, 0, 0, 0, 0, 0, 0};
                if (w >= 0 && w < W)
                    v = *(const b16x8*)(pr + ((size_t)(n * W + w) * C + ci));
                *(b16x8*)&Blds[r * BPITCH + ci] = v;
            }
        }
        __syncthreads();

        // ---- K-loop: 72 iters x (1 A-read + 3 B-reads + 3 MFMA) ----
        f32x4 acc0 = {0.f, 0.f, 0.f, 0.f};
        f32x4 acc1 = {0.f, 0.f, 0.f, 0.f};
        f32x4 acc2 = {0.f, 0.f, 0.f, 0.f};
        const u16* ap = Alds + col * APITCH + kg * 8;
        for (int kk = 0; kk < KW; ++kk) {
            const u16* arow = ap + kk * 256;
            const u16* lrow = &Blds[(col + kk) * BPITCH + kg * 8];
            #pragma unroll
            for (int cb = 0; cb < 8; ++cb) {
                b16x8 a  = *(const b16x8*)(arow + cb * 32);
                const u16* lp = lrow + cb * 32;
                b16x8 b0 = *(const b16x8*)(lp);
                b16x8 b1 = *(const b16x8*)(lp + 16 * BPITCH);
                b16x8 b2 = *(const b16x8*)(lp + 32 * BPITCH);
                acc0 = __builtin_amdgcn_mfma_f32_16x16x32_bf16(a, b0, acc0, 0, 0, 0);
                acc1 = __builtin_amdgcn_mfma_f32_16x16x32_bf16(a, b1, acc1, 0, 0, 0);
                acc2 = __builtin_amdgcn_mfma_f32_16x16x32_bf16(a, b2, acc2, 0, 0, 0);
            }
        }

        // ---- epilogue: bias+relu+residual (prefetched); fp32 out + bf16 carry
        #pragma unroll
        for (int nt = 0; nt < 3; ++nt) {
            f32x4 acc = (nt == 0) ? acc0 : ((nt == 1) ? acc1 : acc2);
            int w = wbase + nt * 16 + col;
            b16x4 cv;
            #pragma unroll
            for (int r = 0; r < 4; ++r) {
                int co = cobase + kg * 4 + r;
                float y = fmaxf(acc[r] + bv[r], 0.f);
                float o = y + resv[nt * 4 + r];
                outp[(size_t)(n * C + co) * HW + row * W + w] = o;
                cv[r] = (short)f2b(o);
            }
            *(b16x4*)(pw + ((size_t)(n * W + w) * C + cobase + kg * 4)) = cv;
        }

        if (s != NSTEP - 1) {
            // ---- release: one waitcnt+wbl2, then per-writer flag store ----
            if (lane == 0)
                __hip_atomic_store(&fl[tile], (unsigned)(s + 1),
                                   __ATOMIC_RELEASE, __HIP_MEMORY_SCOPE_AGENT);

            // ---- prefetch next step's residual (overlaps the spin) ----
            {
                const int   s2    = s + 1;
                const int   row2  = (s2 < H - 1) ? (s2 + 1) : (NSTEP - 1 - s2);
                const float* rp2  = (s2 < H - 1) ? fea : outp;
                #pragma unroll
                for (int nt = 0; nt < 3; ++nt)
                    #pragma unroll
                    for (int r = 0; r < 4; ++r) {
                        int w  = wbase + nt * 16 + col;
                        int co = cobase + kg * 4 + r;
                        resv[nt * 4 + r] =
                            rp2[(size_t)(n * C + co) * HW + row2 * W + w];
                    }
            }

            // ---- relaxed spin: lane i watches flag i; no per-poll fences ----
            {
                const unsigned tgt = (unsigned)(s + 1);
                int guard = 0;
                for (;;) {
                    unsigned v = __hip_atomic_load(&fl[lane & 31], __ATOMIC_RELAXED,
                                                   __HIP_MEMORY_SCOPE_AGENT);
                    if (__all((int)(v >= tgt))) break;
                    __builtin_amdgcn_s_sleep(1);
                    if (++guard > (1 << 22)) break;   // bug -> wrong answer, not hang
                }
            }
            __builtin_amdgcn_fence(__ATOMIC_ACQUIRE, "agent");  // one invl2/step
        }
        u16* t = pr; pr = pw; pw = px; px = t;
    }
}

// ---------------------------------------------------------------------------
extern "C" void kernel_launch(void* const* d_in, const int* in_sizes, int n_in,
                              void* d_out, int out_size, void* d_ws, size_t ws_size,
                              hipStream_t stream)
{
    const float* fea  = (const float*)d_in[0];
    const float* Wsrc = (const float*)d_in[1];
    const float* bias = (const float*)d_in[2];
    float* outp = (float*)d_out;

    u16* Wr = (u16*)d_ws;                        // 589,824 bf16
    u16* c0 = Wr + (size_t)C * K;                // 3 rotating carry buffers
    u16* c1 = c0 + (size_t)HN * W * C;
    u16* c2 = c1 + (size_t)HN * W * C;
    unsigned* flags = (unsigned*)(c2 + (size_t)HN * W * C);  // 8 x 32 u32

    init_k<<<dim3((C * K + 255) / 256), dim3(256), 0, stream>>>(
        fea, Wsrc, Wr, c0, outp, flags);

    void* args[] = { (void*)&Wr, (void*)&bias, (void*)&fea, (void*)&outp,
                     (void*)&c0, (void*)&c1, (void*)&c2, (void*)&flags };
    hipLaunchCooperativeKernel((const void*)persist_k, dim3(256), dim3(64),
                               args, 0, stream);
}

// Round 9
// 2506.748 us; speedup vs baseline: 1.6030x; 1.2134x over previous
//
#include <hip/hip_runtime.h>

typedef short b16x8 __attribute__((ext_vector_type(8)));
typedef short b16x4 __attribute__((ext_vector_type(4)));
typedef float f32x4 __attribute__((ext_vector_type(4)));
typedef unsigned short u16;
typedef unsigned long long u64;

#define HN 8
#define C  256
#define W  96
#define H  96
#define KW 9
#define K  (C * KW)        // 2304
#define HW (H * W)         // 9216
#define BPITCH 264         // carry tile pitch (elems): breaks 512B-stride conflicts
#define BROWS  56          // 48 w + 8 halo
#define APITCH 2312        // W tile pitch (elems): 2304+8 pad -> bank-uniform reads
#define NSTEP  (2 * (H - 1))   // 190 sequential steps

__device__ __forceinline__ u16 f2b(float x) {
    union { float f; unsigned int u; } c; c.f = x;
    unsigned int u = c.u;
    unsigned int r = (u + 0x7fffu + ((u >> 16) & 1u)) >> 16;  // RNE
    return (u16)r;
}

// ---------------------------------------------------------------------------
// init: Wr[co][kk*256+ci] = bf16(W[co][ci][kk]); out row0 = fea row0;
//       carry0[n][w][c] = bf16(fea row0); zero the 8x32 flag slots.
// ---------------------------------------------------------------------------
__global__ void init_k(const float* __restrict__ fea, const float* __restrict__ Wsrc,
                       u16* __restrict__ Wr, u16* __restrict__ carry0,
                       float* __restrict__ outp, unsigned* __restrict__ flags)
{
    int t = blockIdx.x * 256 + threadIdx.x;
    if (t < C * K) {
        int co  = t / K;
        int rme = t - co * K;
        int kk  = rme >> 8;      // K = 9*256 exactly
        int ci  = rme & 255;
        Wr[t] = f2b(Wsrc[(co * C + ci) * KW + kk]);
    }
    if (t < HN * C * W) {
        int n   = t / (C * W);
        int rme = t - n * (C * W);
        int c   = rme / W;
        int w   = rme - c * W;
        float v = fea[(size_t)(n * C + c) * HW + w];     // h = 0
        outp[(size_t)(n * C + c) * HW + w] = v;
        carry0[((size_t)n * W + w) * C + c] = f2b(v);
    }
    if (t < HN * 32) flags[t] = 0u;                      // per-writer flags
}

// ---------------------------------------------------------------------------
// persistent cooperative kernel: 256 blocks x 64 thr (1 wave), 1 block/CU.
// bx -> n = bx&7 (XCD-local sample placement), tile = bx>>3 = (cotile, wh).
// Sync: FENCE-FREE. Carry data moves via relaxed agent atomics (sc1 per-access
// coherence, no wbl2/inv); producer orders data-before-flag with one
// wave-wide s_waitcnt vmcnt(0). 3-buffer carry rotation (read/write/spare).
// ---------------------------------------------------------------------------
__global__ __launch_bounds__(64, 1) void persist_k(
    const u16* __restrict__ Wr, const float* __restrict__ bias,
    const float* __restrict__ fea, float* __restrict__ outp,
    u16* c0, u16* c1, u16* c2, unsigned* flags)
{
    __shared__ __align__(16) u16 Alds[16 * APITCH];       // 73,984 B
    __shared__ __align__(16) u16 Blds[BROWS * BPITCH];    // 29,568 B

    const int bx     = blockIdx.x;
    const int n      = bx & 7;      // sample -> XCD (bx%8 round-robin heuristic)
    const int tile   = bx >> 3;     // 0..31
    const int cotile = tile >> 1;
    const int wh     = tile & 1;
    const int wbase  = wh * 48;
    const int cobase = cotile * 16;
    const int lane   = (int)threadIdx.x;
    const int col    = lane & 15;   // M-row of A, N-col of B, col of D
    const int kg     = lane >> 4;   // k-group (0..3)

    // ---- stage W slice (16 co rows x 2304) into LDS, once ----
    {
        const u16* wsp = Wr + (size_t)cobase * K;         // contiguous slice
        for (int it = 0; it < 72; ++it) {
            int t8  = it * 512 + lane * 8;
            int row = t8 / K;
            int kc  = t8 - row * K;
            b16x8 v = *(const b16x8*)(wsp + t8);
            *(b16x8*)&Alds[row * APITCH + kc] = v;
        }
    }
    float bv[4];
    #pragma unroll
    for (int r = 0; r < 4; ++r) bv[r] = bias[cobase + kg * 4 + r];
    __syncthreads();

    unsigned* fl = flags + n * 32;
    u16 *pr = c0, *pw = c1, *px = c2;

    // prefetch residual for step 0 (row 1, down pass -> fea)
    float resv[12];
    #pragma unroll
    for (int nt = 0; nt < 3; ++nt)
        #pragma unroll
        for (int r = 0; r < 4; ++r) {
            int w  = wbase + nt * 16 + col;
            int co = cobase + kg * 4 + r;
            resv[nt * 4 + r] = fea[(size_t)(n * C + co) * HW + 1 * W + w];
        }

    for (int s = 0; s < NSTEP; ++s) {
        const int row = (s < H - 1) ? (s + 1) : (NSTEP - 1 - s);

        // ---- stage carry row from pr (sc1 coherent 8B loads), zero halo ----
        {
            const int ci = (lane & 31) * 8;
            #pragma unroll
            for (int it = 0; it < 28; ++it) {
                int r = it * 2 + (lane >> 5);      // 0..55
                int w = wbase - 4 + r;
                u64 lo = 0ull, hi = 0ull;
                if (w >= 0 && w < W) {
                    const u64* p = (const u64*)(pr + ((size_t)(n * W + w) * C + ci));
                    lo = __hip_atomic_load(p,     __ATOMIC_RELAXED,
                                           __HIP_MEMORY_SCOPE_AGENT);
                    hi = __hip_atomic_load(p + 1, __ATOMIC_RELAXED,
                                           __HIP_MEMORY_SCOPE_AGENT);
                }
                *(u64*)&Blds[r * BPITCH + ci]     = lo;
                *(u64*)&Blds[r * BPITCH + ci + 4] = hi;
            }
        }
        __syncthreads();

        // ---- K-loop: 72 iters x (1 A-read + 3 B-reads + 3 MFMA) ----
        f32x4 acc0 = {0.f, 0.f, 0.f, 0.f};
        f32x4 acc1 = {0.f, 0.f, 0.f, 0.f};
        f32x4 acc2 = {0.f, 0.f, 0.f, 0.f};
        const u16* ap = Alds + col * APITCH + kg * 8;
        for (int kk = 0; kk < KW; ++kk) {
            const u16* arow = ap + kk * 256;
            const u16* lrow = &Blds[(col + kk) * BPITCH + kg * 8];
            #pragma unroll
            for (int cb = 0; cb < 8; ++cb) {
                b16x8 a  = *(const b16x8*)(arow + cb * 32);
                const u16* lp = lrow + cb * 32;
                b16x8 b0 = *(const b16x8*)(lp);
                b16x8 b1 = *(const b16x8*)(lp + 16 * BPITCH);
                b16x8 b2 = *(const b16x8*)(lp + 32 * BPITCH);
                acc0 = __builtin_amdgcn_mfma_f32_16x16x32_bf16(a, b0, acc0, 0, 0, 0);
                acc1 = __builtin_amdgcn_mfma_f32_16x16x32_bf16(a, b1, acc1, 0, 0, 0);
                acc2 = __builtin_amdgcn_mfma_f32_16x16x32_bf16(a, b2, acc2, 0, 0, 0);
            }
        }

        // ---- epilogue: bias+relu+residual; fp32 out (plain) + bf16 carry (sc1)
        #pragma unroll
        for (int nt = 0; nt < 3; ++nt) {
            f32x4 acc = (nt == 0) ? acc0 : ((nt == 1) ? acc1 : acc2);
            int w = wbase + nt * 16 + col;
            union { b16x4 v; u64 u; } cv;
            #pragma unroll
            for (int r = 0; r < 4; ++r) {
                int co = cobase + kg * 4 + r;
                float y = fmaxf(acc[r] + bv[r], 0.f);
                float o = y + resv[nt * 4 + r];
                outp[(size_t)(n * C + co) * HW + row * W + w] = o;
                cv.v[r] = (short)f2b(o);
            }
            __hip_atomic_store((u64*)(pw + ((size_t)(n * W + w) * C + cobase + kg * 4)),
                               cv.u, __ATOMIC_RELAXED, __HIP_MEMORY_SCOPE_AGENT);
        }

        if (s != NSTEP - 1) {
            // ---- producer order: all sc1 data stores ACKed, then flag ----
            asm volatile("s_waitcnt vmcnt(0)" ::: "memory");
            if (lane == 0)
                __hip_atomic_store(&fl[tile], (unsigned)(s + 1),
                                   __ATOMIC_RELAXED, __HIP_MEMORY_SCOPE_AGENT);

            // ---- prefetch next step's residual (overlaps the spin) ----
            {
                const int   s2    = s + 1;
                const int   row2  = (s2 < H - 1) ? (s2 + 1) : (NSTEP - 1 - s2);
                const float* rp2  = (s2 < H - 1) ? fea : outp;
                #pragma unroll
                for (int nt = 0; nt < 3; ++nt)
                    #pragma unroll
                    for (int r = 0; r < 4; ++r) {
                        int w  = wbase + nt * 16 + col;
                        int co = cobase + kg * 4 + r;
                        resv[nt * 4 + r] =
                            rp2[(size_t)(n * C + co) * HW + row2 * W + w];
                    }
            }

            // ---- relaxed spin: lane i watches flag i; no fences ----
            {
                const unsigned tgt = (unsigned)(s + 1);
                int guard = 0;
                for (;;) {
                    unsigned v = __hip_atomic_load(&fl[lane & 31], __ATOMIC_RELAXED,
                                                   __HIP_MEMORY_SCOPE_AGENT);
                    if (__all((int)(v >= tgt))) break;
                    __builtin_amdgcn_s_sleep(1);
                    if (++guard > (1 << 22)) break;   // bug -> wrong answer, not hang
                }
            }
            asm volatile("" ::: "memory");   // compiler-only ordering; no cache ops
        }
        u16* t = pr; pr = pw; pw = px; px = t;
    }
}

// ---------------------------------------------------------------------------
extern "C" void kernel_launch(void* const* d_in, const int* in_sizes, int n_in,
                              void* d_out, int out_size, void* d_ws, size_t ws_size,
                              hipStream_t stream)
{
    const float* fea  = (const float*)d_in[0];
    const float* Wsrc = (const float*)d_in[1];
    const float* bias = (const float*)d_in[2];
    float* outp = (float*)d_out;

    u16* Wr = (u16*)d_ws;                        // 589,824 bf16
    u16* c0 = Wr + (size_t)C * K;                // 3 rotating carry buffers
    u16* c1 = c0 + (size_t)HN * W * C;
    u16* c2 = c1 + (size_t)HN * W * C;
    unsigned* flags = (unsigned*)(c2 + (size_t)HN * W * C);  // 8 x 32 u32

    init_k<<<dim3((C * K + 255) / 256), dim3(256), 0, stream>>>(
        fea, Wsrc, Wr, c0, outp, flags);

    void* args[] = { (void*)&Wr, (void*)&bias, (void*)&fea, (void*)&outp,
                     (void*)&c0, (void*)&c1, (void*)&c2, (void*)&flags };
    hipLaunchCooperativeKernel((const void*)persist_k, dim3(256), dim3(64),
                               args, 0, stream);
}

// Round 11
// 1270.366 us; speedup vs baseline: 3.1630x; 1.9732x over previous
//
#include <hip/hip_runtime.h>

typedef short b16x8 __attribute__((ext_vector_type(8)));
typedef short b16x4 __attribute__((ext_vector_type(4)));
typedef float f32x4 __attribute__((ext_vector_type(4)));
typedef int   i32x4 __attribute__((ext_vector_type(4)));
typedef unsigned short u16;
typedef unsigned long long u64;

#define HN 8
#define C  256
#define W  96
#define H  96
#define KW 9
#define K  (C * KW)        // 2304
#define HW (H * W)         // 9216
#define CPAD 104           // padded carry rows: 4 zero + 96 + 4 zero
#define BPITCH 264         // carry tile pitch (elems): breaks 512B-stride conflicts
#define BROWS  56          // 48 w + 8 halo
#define APITCH 2312        // W tile pitch (elems): 2304+8 pad -> bank-uniform reads
#define NSTEP  (2 * (H - 1))   // 190 sequential steps

__device__ __forceinline__ u16 f2b(float x) {
    union { float f; unsigned int u; } c; c.f = x;
    unsigned int u = c.u;
    unsigned int r = (u + 0x7fffu + ((u >> 16) & 1u)) >> 16;  // RNE
    return (u16)r;
}

// ---------------------------------------------------------------------------
// init: Wr repack; out row0 = fea row0; carry0 (padded) = bf16(fea row0);
//       zero pad rows of all 3 carry buffers; zero the 8x32 flag slots.
// ---------------------------------------------------------------------------
__global__ void init_k(const float* __restrict__ fea, const float* __restrict__ Wsrc,
                       u16* __restrict__ Wr, u16* __restrict__ c0,
                       u16* __restrict__ c1, u16* __restrict__ c2,
                       float* __restrict__ outp, unsigned* __restrict__ flags)
{
    int t = blockIdx.x * 256 + threadIdx.x;
    if (t < C * K) {
        int co  = t / K;
        int rme = t - co * K;
        int kk  = rme >> 8;      // K = 9*256 exactly
        int ci  = rme & 255;
        Wr[t] = f2b(Wsrc[(co * C + ci) * KW + kk]);
    }
    if (t < HN * C * W) {
        int n   = t / (C * W);
        int rme = t - n * (C * W);
        int c   = rme / W;
        int w   = rme - c * W;
        float v = fea[(size_t)(n * C + c) * HW + w];     // h = 0
        outp[(size_t)(n * C + c) * HW + w] = v;
        c0[((size_t)(n * CPAD + w + 4)) * C + c] = f2b(v);
    }
    if (t < 3 * HN * 8 * C) {                            // zero pad rows
        int b   = t / (HN * 8 * C);
        int rme = t - b * (HN * 8 * C);
        int nn  = rme / (8 * C);
        int rc  = rme - nn * (8 * C);
        int r   = rc / C;                                // 0..7
        int c   = rc - r * C;
        int wi  = (r < 4) ? r : (100 + (r - 4));         // 0..3, 100..103
        u16* cb = (b == 0) ? c0 : ((b == 1) ? c1 : c2);
        cb[((size_t)(nn * CPAD + wi)) * C + c] = 0;
    }
    if (t < HN * 32) flags[t] = 0u;                      // per-writer flags
}

// ---------------------------------------------------------------------------
// persistent cooperative kernel: 256 blocks x 64 thr (1 wave), 1 block/CU.
// bx -> n = bx&7 (XCD-local sample placement), tile = bx>>3 = (cotile, wh).
// Sync: fence-free; carry via device-scope (sc1) accesses. Stage loads are
// BATCHED inline-asm global_load_dwordx4 sc1 (2 waitcnt groups, not 28).
// 3-buffer carry rotation (read/write/spare).
// ---------------------------------------------------------------------------
__global__ __launch_bounds__(64, 1) void persist_k(
    const u16* __restrict__ Wr, const float* __restrict__ bias,
    const float* __restrict__ fea, float* __restrict__ outp,
    u16* c0, u16* c1, u16* c2, unsigned* flags)
{
    __shared__ __align__(16) u16 Alds[16 * APITCH];       // 73,984 B
    __shared__ __align__(16) u16 Blds[BROWS * BPITCH];    // 29,568 B

    const int bx     = blockIdx.x;
    const int n      = bx & 7;      // sample -> XCD (bx%8 round-robin heuristic)
    const int tile   = bx >> 3;     // 0..31
    const int cotile = tile >> 1;
    const int wh     = tile & 1;
    const int wbase  = wh * 48;
    const int cobase = cotile * 16;
    const int lane   = (int)threadIdx.x;
    const int col    = lane & 15;   // M-row of A, N-col of B, col of D
    const int kg     = lane >> 4;   // k-group (0..3)

    // ---- stage W slice (16 co rows x 2304) into LDS, once ----
    {
        const u16* wsp = Wr + (size_t)cobase * K;         // contiguous slice
        for (int it = 0; it < 72; ++it) {
            int t8  = it * 512 + lane * 8;
            int row = t8 / K;
            int kc  = t8 - row * K;
            b16x8 v = *(const b16x8*)(wsp + t8);
            *(b16x8*)&Alds[row * APITCH + kc] = v;
        }
    }
    float bv[4];
    #pragma unroll
    for (int r = 0; r < 4; ++r) bv[r] = bias[cobase + kg * 4 + r];
    __syncthreads();

    unsigned* fl = flags + n * 32;
    u16 *pr = c0, *pw = c1, *px = c2;

    // prefetch residual for step 0 (row 1, down pass -> fea)
    float resv[12];
    #pragma unroll
    for (int nt = 0; nt < 3; ++nt)
        #pragma unroll
        for (int r = 0; r < 4; ++r) {
            int w  = wbase + nt * 16 + col;
            int co = cobase + kg * 4 + r;
            resv[nt * 4 + r] = fea[(size_t)(n * C + co) * HW + 1 * W + w];
        }

    const int ci   = (lane & 31) * 8;
    const int half = lane >> 5;

    for (int s = 0; s < NSTEP; ++s) {
        const int row = (s < H - 1) ? (s + 1) : (NSTEP - 1 - s);

        // ---- stage carry rows [wbase-4, wbase+52) from padded pr ----
        // rows r = 2*it + half; padded w-index = wbase + r (pad offset +4 folded)
        {
            const u16* p0 = pr + ((size_t)(n * CPAD + wbase)) * C + ci + half * C;
            i32x4 va[14];
            #pragma unroll
            for (int it = 0; it < 14; ++it) {
                const u16* a = p0 + (size_t)(it * 2) * C;
                asm volatile("global_load_dwordx4 %0, %1, off sc1"
                             : "=v"(va[it]) : "v"(a) : "memory");
            }
            asm volatile("s_waitcnt vmcnt(0)" ::: "memory");
            #pragma unroll
            for (int it = 0; it < 14; ++it)
                *(i32x4*)&Blds[(it * 2 + half) * BPITCH + ci] = va[it];
            i32x4 vb[14];
            #pragma unroll
            for (int it = 0; it < 14; ++it) {
                const u16* a = p0 + (size_t)(28 + it * 2) * C;
                asm volatile("global_load_dwordx4 %0, %1, off sc1"
                             : "=v"(vb[it]) : "v"(a) : "memory");
            }
            asm volatile("s_waitcnt vmcnt(0)" ::: "memory");
            #pragma unroll
            for (int it = 0; it < 14; ++it)
                *(i32x4*)&Blds[(28 + it * 2 + half) * BPITCH + ci] = vb[it];
        }
        __syncthreads();

        // ---- K-loop: 72 iters x (1 A-read + 3 B-reads + 3 MFMA) ----
        f32x4 acc0 = {0.f, 0.f, 0.f, 0.f};
        f32x4 acc1 = {0.f, 0.f, 0.f, 0.f};
        f32x4 acc2 = {0.f, 0.f, 0.f, 0.f};
        const u16* ap = Alds + col * APITCH + kg * 8;
        for (int kk = 0; kk < KW; ++kk) {
            const u16* arow = ap + kk * 256;
            const u16* lrow = &Blds[(col + kk) * BPITCH + kg * 8];
            #pragma unroll
            for (int cb = 0; cb < 8; ++cb) {
                b16x8 a  = *(const b16x8*)(arow + cb * 32);
                const u16* lp = lrow + cb * 32;
                b16x8 b0 = *(const b16x8*)(lp);
                b16x8 b1 = *(const b16x8*)(lp + 16 * BPITCH);
                b16x8 b2 = *(const b16x8*)(lp + 32 * BPITCH);
                acc0 = __builtin_amdgcn_mfma_f32_16x16x32_bf16(a, b0, acc0, 0, 0, 0);
                acc1 = __builtin_amdgcn_mfma_f32_16x16x32_bf16(a, b1, acc1, 0, 0, 0);
                acc2 = __builtin_amdgcn_mfma_f32_16x16x32_bf16(a, b2, acc2, 0, 0, 0);
            }
        }

        // ---- epilogue: bias+relu+residual; fp32 out (plain) + bf16 carry (sc1)
        #pragma unroll
        for (int nt = 0; nt < 3; ++nt) {
            f32x4 acc = (nt == 0) ? acc0 : ((nt == 1) ? acc1 : acc2);
            int w = wbase + nt * 16 + col;
            union { b16x4 v; u64 u; } cv;
            #pragma unroll
            for (int r = 0; r < 4; ++r) {
                int co = cobase + kg * 4 + r;
                float y = fmaxf(acc[r] + bv[r], 0.f);
                float o = y + resv[nt * 4 + r];
                outp[(size_t)(n * C + co) * HW + row * W + w] = o;
                cv.v[r] = (short)f2b(o);
            }
            __hip_atomic_store(
                (u64*)(pw + ((size_t)(n * CPAD + w + 4)) * C + cobase + kg * 4),
                cv.u, __ATOMIC_RELAXED, __HIP_MEMORY_SCOPE_AGENT);
        }

        if (s != NSTEP - 1) {
            // ---- producer order: all sc1 data stores ACKed, then flag ----
            asm volatile("s_waitcnt vmcnt(0)" ::: "memory");
            if (lane == 0)
                __hip_atomic_store(&fl[tile], (unsigned)(s + 1),
                                   __ATOMIC_RELAXED, __HIP_MEMORY_SCOPE_AGENT);

            // ---- prefetch next step's residual (overlaps the spin) ----
            {
                const int   s2    = s + 1;
                const int   row2  = (s2 < H - 1) ? (s2 + 1) : (NSTEP - 1 - s2);
                const float* rp2  = (s2 < H - 1) ? fea : outp;
                #pragma unroll
                for (int nt = 0; nt < 3; ++nt)
                    #pragma unroll
                    for (int r = 0; r < 4; ++r) {
                        int w  = wbase + nt * 16 + col;
                        int co = cobase + kg * 4 + r;
                        resv[nt * 4 + r] =
                            rp2[(size_t)(n * C + co) * HW + row2 * W + w];
                    }
            }

            // ---- relaxed spin: lane i watches flag i; no fences ----
            {
                const unsigned tgt = (unsigned)(s + 1);
                int guard = 0;
                for (;;) {
                    unsigned v = __hip_atomic_load(&fl[lane & 31], __ATOMIC_RELAXED,
                                                   __HIP_MEMORY_SCOPE_AGENT);
                    if (__all((int)(v >= tgt))) break;
                    __builtin_amdgcn_s_sleep(1);
                    if (++guard > (1 << 22)) break;   // bug -> wrong answer, not hang
                }
            }
            asm volatile("" ::: "memory");   // compiler-only ordering; no cache ops
        }
        u16* t = pr; pr = pw; pw = px; px = t;
    }
}

// ---------------------------------------------------------------------------
extern "C" void kernel_launch(void* const* d_in, const int* in_sizes, int n_in,
                              void* d_out, int out_size, void* d_ws, size_t ws_size,
                              hipStream_t stream)
{
    const float* fea  = (const float*)d_in[0];
    const float* Wsrc = (const float*)d_in[1];
    const float* bias = (const float*)d_in[2];
    float* outp = (float*)d_out;

    u16* Wr = (u16*)d_ws;                        // 589,824 bf16
    u16* c0 = Wr + (size_t)C * K;                // 3 rotating padded carry buffers
    u16* c1 = c0 + (size_t)HN * CPAD * C;
    u16* c2 = c1 + (size_t)HN * CPAD * C;
    unsigned* flags = (unsigned*)(c2 + (size_t)HN * CPAD * C);  // 8 x 32 u32

    init_k<<<dim3((C * K + 255) / 256), dim3(256), 0, stream>>>(
        fea, Wsrc, Wr, c0, c1, c2, outp, flags);

    void* args[] = { (void*)&Wr, (void*)&bias, (void*)&fea, (void*)&outp,
                     (void*)&c0, (void*)&c1, (void*)&c2, (void*)&flags };
    hipLaunchCooperativeKernel((const void*)persist_k, dim3(256), dim3(64),
                               args, 0, stream);
}